// Round 11
// baseline (558.733 us; speedup 1.0000x reference)
//
#include <hip/hip_runtime.h>
#include <hip/hip_bf16.h>

#define B_SZ 128
#define K_SZ 65536
#define H_SZ 768
#define TOPK 5
#define NEG_MIN 64512
#define OUTC 64513            // NEG_MIN + 1
#define NBINS 65536
#define INV_T (1.0f/0.07f)
#define SEGS 8
#define SEG_BINS 8192         // NBINS / SEGS

typedef __attribute__((ext_vector_type(8))) short short8;
typedef __attribute__((ext_vector_type(4))) float f32x4;

// ---- bf16 / sortable-key helpers -------------------------------------------
__device__ __forceinline__ unsigned short f32_bf16(float v) {
    unsigned u = __float_as_uint(v);
    unsigned r = ((u >> 16) & 1u) + 0x7FFFu;
    return (unsigned short)((u + r) >> 16);              // RNE bf16 bits
}
__device__ __forceinline__ unsigned f32_key(float v) {
    unsigned u = __float_as_uint(v);
    unsigned r = ((u >> 16) & 1u) + 0x7FFFu;
    unsigned b = (u + r) >> 16;
    return (b & 0x8000u) ? (0xFFFFu & ~b) : (b | 0x8000u);
}
__device__ __forceinline__ float key_val(unsigned key) {
    unsigned b = (key & 0x8000u) ? (key ^ 0x8000u) : (0xFFFFu & ~key);
    return __uint_as_float(b << 16);
}
// padded LDS index: +1 word per 32 to break stride-32 bank aliasing
__device__ __forceinline__ int fpad(int d) { return d + (d >> 5); }

// ---- kernel 1: l2-normalize q -> bf16 --------------------------------------
__global__ __launch_bounds__(256) void norm_kernel(const float* __restrict__ q,
                                                   unsigned short* __restrict__ qn) {
    __shared__ float red[256];
    const int b = blockIdx.x, t = threadIdx.x;
    float s = 0.f;
    for (int h = t; h < H_SZ; h += 256) { float v = q[b*H_SZ + h]; s += v*v; }
    red[t] = s; __syncthreads();
    for (int off = 128; off > 0; off >>= 1) {
        if (t < off) red[t] += red[t + off];
        __syncthreads();
    }
    const float inv = 1.0f / sqrtf(red[0]);
    for (int h = t; h < H_SZ; h += 256) qn[b*H_SZ + h] = f32_bf16(q[b*H_SZ + h] * inv);
}

// ---- kernel 2: bf16 MFMA GEMM -> u16 sortable keys (unchanged) --------------
__global__ __launch_bounds__(256) void gemm_key_kernel(
    const unsigned short* __restrict__ qn, const float* __restrict__ fq,
    unsigned* __restrict__ hist)
{
    __shared__ unsigned short Fs[128][40];
    __shared__ unsigned short Qs[128][40];
    const int tid  = threadIdx.x;
    const int lane = tid & 63;
    const int w    = tid >> 6;
    const int k_base = blockIdx.x * 128;

    f32x4 acc[2][8];
#pragma unroll
    for (int mg = 0; mg < 2; ++mg)
#pragma unroll
        for (int bg = 0; bg < 8; ++bg) acc[mg][bg] = (f32x4){0.f, 0.f, 0.f, 0.f};

    for (int kc = 0; kc < H_SZ/32; ++kc) {
        const int c0 = kc * 32;
        __syncthreads();
#pragma unroll
        for (int it = 0; it < 4; ++it) {
            const int task = it*256 + tid;
            const int r = task >> 3, q = task & 7;
            const float4 v = *(const float4*)(fq + (size_t)(k_base + r)*H_SZ + c0 + q*4);
            ushort4 b4;
            b4.x = f32_bf16(v.x); b4.y = f32_bf16(v.y);
            b4.z = f32_bf16(v.z); b4.w = f32_bf16(v.w);
            *(ushort4*)(&Fs[r][q*4]) = b4;
        }
#pragma unroll
        for (int it = 0; it < 2; ++it) {
            const int task = it*256 + tid;
            const int r = task >> 2, h = task & 3;
            const uint4 v = *(const uint4*)(qn + (size_t)r*H_SZ + c0 + h*8);
            *(uint4*)(&Qs[r][h*8]) = v;
        }
        __syncthreads();
        const int ko = (lane >> 4) * 8;
        short8 a[2], bq[8];
        a[0] = *(const short8*)(&Fs[w*32      + (lane & 15)][ko]);
        a[1] = *(const short8*)(&Fs[w*32 + 16 + (lane & 15)][ko]);
#pragma unroll
        for (int bg = 0; bg < 8; ++bg)
            bq[bg] = *(const short8*)(&Qs[bg*16 + (lane & 15)][ko]);
#pragma unroll
        for (int mg = 0; mg < 2; ++mg)
#pragma unroll
            for (int bg = 0; bg < 8; ++bg)
                acc[mg][bg] = __builtin_amdgcn_mfma_f32_16x16x32_bf16(
                    a[mg], bq[bg], acc[mg][bg], 0, 0, 0);
    }

    const int col  = lane & 15;
    const int rgrp = (lane >> 4) * 4;
#pragma unroll
    for (int mg = 0; mg < 2; ++mg)
#pragma unroll
        for (int bg = 0; bg < 8; ++bg) {
            ushort4 kk;
            kk.x = (unsigned short)f32_key(acc[mg][bg][0]);
            kk.y = (unsigned short)f32_key(acc[mg][bg][1]);
            kk.z = (unsigned short)f32_key(acc[mg][bg][2]);
            kk.w = (unsigned short)f32_key(acc[mg][bg][3]);
            unsigned short* dst = (unsigned short*)(hist + (size_t)(bg*16 + col)*NBINS)
                                  + (k_base + w*32 + mg*16 + rgrp);
            *(ushort4*)dst = kk;
        }
}

// ---- kernel 3: per-row histogram via 128KB LDS (unchanged) ------------------
__global__ __launch_bounds__(256) void hist_kernel(
    const int* __restrict__ lq, const int* __restrict__ lk,
    unsigned* __restrict__ hist)
{
    __shared__ unsigned packed[NBINS/2];      // 131072 B
    __shared__ unsigned short plist[1152];
    __shared__ unsigned pcount;
    const int row = blockIdx.x, t = threadIdx.x;
#pragma unroll
    for (int i = 0; i < 128; ++i) packed[i*256 + t] = 0;
    if (t == 0) pcount = 0;
    const int myl = lq[row];
    unsigned* hrow = hist + (size_t)row*NBINS;
    const uint4* kp = (const uint4*)hrow;
    __syncthreads();

    for (int it = 0; it < 32; ++it) {
        const int idx = it*256 + t;
        const uint4 kv = kp[idx];
        const int4 l0 = ((const int4*)lk)[idx*2];
        const int4 l1 = ((const int4*)lk)[idx*2 + 1];
        unsigned ks[8] = { kv.x & 0xFFFFu, kv.x >> 16, kv.y & 0xFFFFu, kv.y >> 16,
                           kv.z & 0xFFFFu, kv.z >> 16, kv.w & 0xFFFFu, kv.w >> 16 };
        int ls[8] = { l0.x, l0.y, l0.z, l0.w, l1.x, l1.y, l1.z, l1.w };
#pragma unroll
        for (int j = 0; j < 8; ++j) {
            atomicAdd(&packed[ks[j] >> 1], (ks[j] & 1u) ? 0x10000u : 1u);
            if (ls[j] == myl) {
                unsigned p = atomicAdd(&pcount, 1u);
                if (p < 1152) plist[p] = (unsigned short)ks[j];
            }
        }
    }
    __syncthreads();
    for (int i = 0; i < 32; ++i) {
        const int idx = i*256 + t;
        const uint4 pw = ((const uint4*)packed)[idx];
        uint4 o0, o1;
        o0.x = pw.x & 0xFFFFu; o0.y = pw.x >> 16; o0.z = pw.y & 0xFFFFu; o0.w = pw.y >> 16;
        o1.x = pw.z & 0xFFFFu; o1.y = pw.z >> 16; o1.z = pw.w & 0xFFFFu; o1.w = pw.w >> 16;
        ((uint4*)hrow)[idx*2]     = o0;
        ((uint4*)hrow)[idx*2 + 1] = o1;
    }
    __syncthreads();
    const unsigned np = pcount < 1152u ? pcount : 1152u;
    for (unsigned p = t; p < np; p += 256)
        atomicAdd(&hrow[plist[p]], 0xFFFFu);   // neg -= 1, pos += 1
}

// ---- wave scan helper -------------------------------------------------------
__device__ __forceinline__ void wave_scan2(int lane, unsigned& sn, unsigned& sa) {
#pragma unroll
    for (int off = 1; off < 64; off <<= 1) {
        unsigned un = __shfl_up(sn, off, 64);
        unsigned ua = __shfl_up(sa, off, 64);
        if (lane >= off) { sn += un; sa += ua; }
    }
}

// ---- kernel 4: chunk scan + pos_sample (top-5 over ALL) ---------------------
__global__ __launch_bounds__(256) void scan_kernel(
    const unsigned* __restrict__ hist, unsigned* __restrict__ offs,
    float* __restrict__ out)
{
    __shared__ unsigned cn[256], ca[256];
    __shared__ unsigned wn[4], wa[4];
    const int row = blockIdx.x, t = threadIdx.x;
    const int wv = t >> 6, lane = t & 63;
    const uint4* hp = (const uint4*)(hist + (size_t)row*NBINS);
    for (int i = 0; i < 64; ++i) {
        const uint4 v = hp[i*256 + t];
        unsigned n = (v.x & 0xFFFFu) + (v.y & 0xFFFFu) + (v.z & 0xFFFFu) + (v.w & 0xFFFFu);
        unsigned a = (v.x >> 16)     + (v.y >> 16)     + (v.z >> 16)     + (v.w >> 16);
#pragma unroll
        for (int off = 1; off < 64; off <<= 1) {
            n += __shfl_xor(n, off, 64);
            a += __shfl_xor(a, off, 64);
        }
        if (lane == 0) { cn[i*4 + wv] = n; ca[i*4 + wv] = a; }
    }
    __syncthreads();
    const unsigned vn = cn[255 - t];
    const unsigned va = ca[255 - t] + vn;          // all = neg + pos
    unsigned sn = vn, sa = va;
    wave_scan2(lane, sn, sa);
    if (lane == 63) { wn[wv] = sn; wa[wv] = sa; }
    __syncthreads();
    unsigned pn = 0, pa = 0;
    for (int i = 0; i < wv; ++i) { pn += wn[i]; pa += wa[i]; }
    const unsigned eneg = pn + sn - vn;
    const unsigned eall = pa + sa - va;
    offs[((size_t)row*256 + t)*2 + 0] = eneg;
    offs[((size_t)row*256 + t)*2 + 1] = eall;

    // pos_sample: chunks whose exclusive all-prefix < TOPK walk their bins
    if (eall < TOPK) {
        const unsigned* hrow = hist + (size_t)row*NBINS;
        unsigned r = eall;
        for (int j = 0; j < 256 && r < TOPK; ++j) {
            const unsigned key = 65535u - (unsigned)(t*256 + j);
            const unsigned w = hrow[key];
            const unsigned cnt = (w & 0xFFFFu) + (w >> 16);
            if (cnt) {
                const float val = key_val(key) * INV_T;
                unsigned end = r + cnt; if (end > TOPK) end = TOPK;
                for (unsigned rr = r; rr < end; ++rr)
                    out[((size_t)row*TOPK + rr)*OUTC] = val;
                r += cnt;
            }
        }
    }
}

// ---- kernel 5: emission — 8 segments/row, LDS prefix + rank decode ----------
// Block (seg s, row): owns 8192 DESC bins. Builds padded prefix C(0..8192) in
// LDS, then streams the segment's elements: binary search -> bin -> value,
// 5 coalesced replica streams. Writes only cols [1, 64513).
__global__ __launch_bounds__(256) void emit_kernel(
    const unsigned* __restrict__ hist, const unsigned* __restrict__ offs,
    float* __restrict__ out)
{
    __shared__ unsigned A[8449];          // fpad(8192)=8448, +1
    __shared__ unsigned tsum[256];
    __shared__ unsigned wsum[4];
    const int s = blockIdx.x, row = blockIdx.y, t = threadIdx.x;
    const unsigned* hrow = hist + (size_t)row*NBINS;

    // phase 1: neg counts into C-slot d+1 (coalesced hist reads)
    for (int j = 0; j < 32; ++j) {
        const int d = j*256 + t;                       // local DESC bin
        const unsigned key = 65535u - (unsigned)(s*SEG_BINS + d);
        A[fpad(d + 1)] = hrow[key] & 0xFFFFu;
    }
    __syncthreads();
    // phase 2: serial prefix within thread's 32 slots
    unsigned run = 0;
#pragma unroll
    for (int i = 0; i < 32; ++i) {
        const int d = t*32 + 1 + i;
        run += A[fpad(d)];
        A[fpad(d)] = run;
    }
    tsum[t] = run;
    __syncthreads();
    // phase 3: block-exclusive scan of tsum; phase 4: add back
    {
        const int wv = t >> 6, lane = t & 63;
        unsigned v = tsum[t], sv = v;
#pragma unroll
        for (int off = 1; off < 64; off <<= 1) {
            unsigned u = __shfl_up(sv, off, 64);
            if (lane >= off) sv += u;
        }
        if (lane == 63) wsum[wv] = sv;
        __syncthreads();
        unsigned p = 0;
        for (int i = 0; i < wv; ++i) p += wsum[i];
        const unsigned excl = p + sv - v;
#pragma unroll
        for (int i = 0; i < 32; ++i) {
            const int d = t*32 + 1 + i;
            A[fpad(d)] += excl;
        }
        if (t == 0) A[fpad(0)] = 0;
    }
    __syncthreads();

    const unsigned S    = A[fpad(8192)];
    const unsigned base = offs[((size_t)row*256 + s*32)*2 + 0];
    float* orow = out + (size_t)row*TOPK*OUTC + 1 + base;
    for (unsigned e = t; e < S; e += 256) {
        int lo = 0, hi = 8191;
#pragma unroll
        for (int i = 0; i < 13; ++i) {
            const int mid = (lo + hi) >> 1;
            if (A[fpad(mid + 1)] > e) hi = mid; else lo = mid + 1;
        }
        const unsigned key = 65535u - (unsigned)(s*SEG_BINS + lo);
        const float v = key_val(key) * INV_T;
        orow[e]          = v;
        orow[OUTC   + e] = v;
        orow[2*OUTC + e] = v;
        orow[3*OUTC + e] = v;
        orow[4*OUTC + e] = v;
    }
}

extern "C" void kernel_launch(void* const* d_in, const int* in_sizes, int n_in,
                              void* d_out, int out_size, void* d_ws, size_t ws_size,
                              hipStream_t stream)
{
    (void)in_sizes; (void)n_in; (void)out_size; (void)ws_size;
    const float* liner_q = (const float*)d_in[0];
    const float* fq      = (const float*)d_in[1];
    const int*   lq      = (const int*)d_in[2];
    const int*   lk      = (const int*)d_in[3];
    float* out = (float*)d_out;

    char* ws = (char*)d_ws;
    unsigned short* qn   = (unsigned short*)ws;           // 196,608 B
    unsigned*       offs = (unsigned*)(ws + 196608);      // 262,144 B
    unsigned*       hist = (unsigned*)(ws + 458752);      // 33,554,432 B (keys aliased)

    norm_kernel<<<B_SZ, 256, 0, stream>>>(liner_q, qn);
    gemm_key_kernel<<<K_SZ/128, 256, 0, stream>>>(qn, fq, hist);
    hist_kernel<<<B_SZ, 256, 0, stream>>>(lq, lk, hist);
    scan_kernel<<<B_SZ, 256, 0, stream>>>(hist, offs, out);
    emit_kernel<<<dim3(SEGS, B_SZ), 256, 0, stream>>>(hist, offs, out);
}